// Round 8
// baseline (367.860 us; speedup 1.0000x reference)
//
#include <hip/hip_runtime.h>
#include <hip/hip_bf16.h>

#define NNODES 10000
#define NEDGES 160000
#define ETOT   (NEDGES + NNODES)
#define CIN    256
#define CH     512     // HID*H
#define NHEAD  8
#define HDIM   64
#define COUT   16
#define NEG_SLOPE 0.2f
#define NF ((size_t)NNODES * CH)

// ---------- bf16 helpers (bit-level, round-to-nearest-even) ----------
__device__ __forceinline__ float bf2f(uint u) {
    union { uint i; float f; } v; v.i = u << 16; return v.f;
}
__device__ __forceinline__ ushort f2bf(float x) {
    union { float f; uint i; } v; v.f = x;
    uint r = v.i + 0x7fff + ((v.i >> 16) & 1);
    return (ushort)(r >> 16);
}

typedef __attribute__((ext_vector_type(8))) short short8v;
typedef __attribute__((ext_vector_type(4))) float f32x4;

// ---------------- CSR build ----------------
__global__ void count_deg_k(const int* __restrict__ ei, int* __restrict__ deg) {
    int eid = blockIdx.x * 256 + threadIdx.x;
    if (eid >= ETOT) return;
    int dst = (eid < NEDGES) ? ei[NEDGES + eid] : (eid - NEDGES);
    atomicAdd(&deg[dst], 1);
}

__global__ __launch_bounds__(512) void scan_k(const int* __restrict__ deg, int* __restrict__ startA) {
    __shared__ int partial[512];
    int t = threadIdx.x;
    const int per = (NNODES + 511) / 512;  // 20
    int base = t * per;
    int s = 0;
    for (int j = 0; j < per; ++j) { int idx = base + j; if (idx < NNODES) s += deg[idx]; }
    partial[t] = s;
    __syncthreads();
    for (int off = 1; off < 512; off <<= 1) {
        int v = (t >= off) ? partial[t - off] : 0;
        __syncthreads();
        partial[t] += v;
        __syncthreads();
    }
    int run = (t == 0) ? 0 : partial[t - 1];
    for (int j = 0; j < per; ++j) {
        int idx = base + j;
        if (idx < NNODES) { startA[idx] = run; run += deg[idx]; }
    }
}

__global__ void scatter_k(const int* __restrict__ ei, const int* __restrict__ startA,
                          int* __restrict__ cursor, int* __restrict__ csr_src) {
    int eid = blockIdx.x * 256 + threadIdx.x;
    if (eid >= ETOT) return;
    int src, dst;
    if (eid < NEDGES) { src = ei[eid]; dst = ei[NEDGES + eid]; }
    else { src = dst = eid - NEDGES; }
    int pos = startA[dst] + atomicAdd(&cursor[dst], 1);
    csr_src[pos] = src;
}

// ---------------- converts ----------------
__global__ void convert_x_k(const float* __restrict__ x, ushort* __restrict__ xb) {
    int idx = blockIdx.x * 256 + threadIdx.x;
    if (idx >= NNODES * CIN / 4) return;
    float4 v = ((const float4*)x)[idx];
    ushort4 o; o.x = f2bf(v.x); o.y = f2bf(v.y); o.z = f2bf(v.z); o.w = f2bf(v.w);
    ((ushort4*)xb)[idx] = o;
}

// W[K][N] fp32 -> Wt[N][K] bf16, 32x32 LDS tile transpose
__global__ __launch_bounds__(256) void convert_wT_k(const float* __restrict__ W, ushort* __restrict__ Wt,
                                                    int K, int N) {
    __shared__ float tile[32][33];
    int tx = threadIdx.x & 31, ty = threadIdx.x >> 5;  // 32x8
    int n0 = blockIdx.x * 32, k0 = blockIdx.y * 32;
#pragma unroll
    for (int r = 0; r < 32; r += 8)
        tile[ty + r][tx] = W[(size_t)(k0 + ty + r) * N + n0 + tx];
    __syncthreads();
#pragma unroll
    for (int r = 0; r < 32; r += 8)
        Wt[(size_t)(n0 + ty + r) * K + k0 + tx] = f2bf(tile[tx][ty + r]);
}

// ---------------- bf16 MFMA GEMM: C[M,CH] = A[M,K] @ Bt[CH,K]^T (+bias), bf16 out ----------
// 64x64 tile, 4 waves (2x2), 16x16x32 MFMA, BK=32  [round-4 measured-best for N=512]
#define LDK 40  // padded LDS row (bf16 elems): 80B stride
__global__ __launch_bounds__(256) void gemm_mfma(const ushort* __restrict__ A, const ushort* __restrict__ Bt,
                                                 const float* __restrict__ bias, ushort* __restrict__ C,
                                                 int M, int K) {
    __shared__ ushort Asl[64 * LDK];
    __shared__ ushort Bsl[64 * LDK];
    int t = threadIdx.x;
    int wid = t >> 6, lane = t & 63;
    int row0 = blockIdx.x * 64, col0 = blockIdx.y * 64;
    int wr = (wid >> 1) * 32, wc = (wid & 1) * 32;
    f32x4 acc[2][2] = {};
    int sRow = t >> 2;        // 0..63
    int sK = (t & 3) * 8;     // 0,8,16,24
    int lr = lane & 15;
    int kg = (lane >> 4) * 8;

    for (int k0 = 0; k0 < K; k0 += 32) {
        int gr = row0 + sRow;
        uint4 av = {0u, 0u, 0u, 0u};
        if (gr < M) av = *(const uint4*)(A + (size_t)gr * K + k0 + sK);
        *(uint4*)(&Asl[sRow * LDK + sK]) = av;
        uint4 bv = *(const uint4*)(Bt + (size_t)(col0 + sRow) * K + k0 + sK);
        *(uint4*)(&Bsl[sRow * LDK + sK]) = bv;
        __syncthreads();
        short8v a0 = *(const short8v*)(&Asl[(wr + lr) * LDK + kg]);
        short8v a1 = *(const short8v*)(&Asl[(wr + 16 + lr) * LDK + kg]);
        short8v b0 = *(const short8v*)(&Bsl[(wc + lr) * LDK + kg]);
        short8v b1 = *(const short8v*)(&Bsl[(wc + 16 + lr) * LDK + kg]);
        acc[0][0] = __builtin_amdgcn_mfma_f32_16x16x32_bf16(a0, b0, acc[0][0], 0, 0, 0);
        acc[0][1] = __builtin_amdgcn_mfma_f32_16x16x32_bf16(a0, b1, acc[0][1], 0, 0, 0);
        acc[1][0] = __builtin_amdgcn_mfma_f32_16x16x32_bf16(a1, b0, acc[1][0], 0, 0, 0);
        acc[1][1] = __builtin_amdgcn_mfma_f32_16x16x32_bf16(a1, b1, acc[1][1], 0, 0, 0);
        __syncthreads();
    }
    // C/D layout: col = lane&15, row = (lane>>4)*4 + j   [m89-verified]
#pragma unroll
    for (int mf = 0; mf < 2; ++mf) {
#pragma unroll
        for (int nf = 0; nf < 2; ++nf) {
            int c = col0 + wc + nf * 16 + lr;
            float bb = bias ? bias[c] : 0.f;
#pragma unroll
            for (int j = 0; j < 4; ++j) {
                int r = row0 + wr + mf * 16 + (lane >> 4) * 4 + j;
                if (r < M) C[(size_t)r * CH + c] = f2bf(acc[mf][nf][j] + bb);
            }
        }
    }
}

// ---------------- LN + ELU on bf16 (128 thr, 4 ch/thread) ----------------
__global__ __launch_bounds__(128) void ln_elu_k(const ushort* __restrict__ inb, const float* __restrict__ g,
                                                const float* __restrict__ b, ushort* __restrict__ outb) {
    int i = blockIdx.x, t = threadIdx.x;
    uint2 hv = ((const uint2*)(inb + (size_t)i * CH))[t];
    float a0 = bf2f(hv.x & 0xffff), a1 = bf2f(hv.x >> 16);
    float a2 = bf2f(hv.y & 0xffff), a3 = bf2f(hv.y >> 16);
    float s = a0 + a1 + a2 + a3;
    float s2 = a0 * a0 + a1 * a1 + a2 * a2 + a3 * a3;
#pragma unroll
    for (int off = 1; off < 64; off <<= 1) { s += __shfl_xor(s, off); s2 += __shfl_xor(s2, off); }
    __shared__ float sh[4];
    int wid = t >> 6, lane = t & 63;
    if (lane == 0) { sh[wid] = s; sh[2 + wid] = s2; }
    __syncthreads();
    float tot = sh[0] + sh[1], tot2 = sh[2] + sh[3];
    float mean = tot * (1.0f / CH);
    float var = tot2 * (1.0f / CH) - mean * mean;
    float rstd = rsqrtf(var + 1e-5f);
    float4 gv = ((const float4*)g)[t];
    float4 bv = ((const float4*)b)[t];
    float y0 = (a0 - mean) * rstd * gv.x + bv.x; y0 = y0 > 0.f ? y0 : __expf(y0) - 1.f;
    float y1 = (a1 - mean) * rstd * gv.y + bv.y; y1 = y1 > 0.f ? y1 : __expf(y1) - 1.f;
    float y2 = (a2 - mean) * rstd * gv.z + bv.z; y2 = y2 > 0.f ? y2 : __expf(y2) - 1.f;
    float y3 = (a3 - mean) * rstd * gv.w + bv.w; y3 = y3 > 0.f ? y3 : __expf(y3) - 1.f;
    ushort4 o; o.x = f2bf(y0); o.y = f2bf(y1); o.z = f2bf(y2); o.w = f2bf(y3);
    ((ushort4*)(outb + (size_t)i * CH))[t] = o;
}

// ---------------- attention logits (8 heads, bf16 h) ----------------
__global__ void attn_logits_k(const ushort* __restrict__ h, const float* __restrict__ a_src,
                              const float* __restrict__ a_dst, float* __restrict__ als,
                              float* __restrict__ ald) {
    int idx = blockIdx.x * 256 + threadIdx.x;
    if (idx >= NNODES * NHEAD) return;
    int i = idx >> 3, hh = idx & 7;
    const uint2* hp = (const uint2*)(h + (size_t)i * CH + hh * HDIM);
    const float* sp = a_src + hh * HDIM;
    const float* dp = a_dst + hh * HDIM;
    float s = 0.f, d = 0.f;
#pragma unroll
    for (int j = 0; j < HDIM / 4; ++j) {
        uint2 v = hp[j];
        float h0 = bf2f(v.x & 0xffff), h1 = bf2f(v.x >> 16);
        float h2 = bf2f(v.y & 0xffff), h3 = bf2f(v.y >> 16);
        s += h0 * sp[j * 4] + h1 * sp[j * 4 + 1] + h2 * sp[j * 4 + 2] + h3 * sp[j * 4 + 3];
        d += h0 * dp[j * 4] + h1 * dp[j * 4 + 1] + h2 * dp[j * 4 + 2] + h3 * dp[j * 4 + 3];
    }
    als[idx] = s; ald[idx] = d;
}

// -------- FUSED two-pass softmax gather + bias + LN + ELU + residual -----------
// block = 1 node, 128 thr, 4 ch/thread; head group = 16 threads (redundant m/s math).
// Pass 1: max over edges (cheap, als only). Pass 2: p=exp(ee-m) fixed-m -> INDEPENDENT
// iterations so the h-row gathers pipeline (round-6 online version was a serial chain).
__global__ __launch_bounds__(128) void agg_ln_k(const ushort* __restrict__ hb, const float* __restrict__ als,
                                                const float* __restrict__ ald, const int* __restrict__ startA,
                                                const int* __restrict__ deg, const int* __restrict__ csr,
                                                const float* __restrict__ bias, const float* __restrict__ gamma,
                                                const float* __restrict__ beta, const ushort* __restrict__ residb,
                                                ushort* __restrict__ outb) {
    int i = blockIdx.x, t = threadIdx.x;
    int c0 = t * 4, head = t >> 4;
    int s0 = startA[i], d = deg[i];
    float aldv = ald[i * NHEAD + head];
    const int* cp = csr + s0;
    // pass 1: segment max
    float m = -1e30f;
    for (int e = 0; e < d; ++e) {
        int src = cp[e];
        float ee = als[src * NHEAD + head] + aldv;
        ee = ee > 0.f ? ee : NEG_SLOPE * ee;
        m = fmaxf(m, ee);
    }
    // pass 2: weighted gather with independent iterations
    float ssum = 0.f;
    float a0 = 0.f, a1 = 0.f, a2 = 0.f, a3 = 0.f;
    for (int e = 0; e < d; ++e) {
        int src = cp[e];
        float ee = als[src * NHEAD + head] + aldv;
        ee = ee > 0.f ? ee : NEG_SLOPE * ee;
        float p = __expf(ee - m);
        ssum += p;
        uint2 hv = *(const uint2*)(hb + (size_t)src * CH + c0);
        a0 += p * bf2f(hv.x & 0xffff); a1 += p * bf2f(hv.x >> 16);
        a2 += p * bf2f(hv.y & 0xffff); a3 += p * bf2f(hv.y >> 16);
    }
    float inv = 1.0f / (ssum + 1e-16f);
    float4 bi = ((const float4*)bias)[t];
    a0 = a0 * inv + bi.x; a1 = a1 * inv + bi.y; a2 = a2 * inv + bi.z; a3 = a3 * inv + bi.w;
    float s = a0 + a1 + a2 + a3;
    float s2 = a0 * a0 + a1 * a1 + a2 * a2 + a3 * a3;
#pragma unroll
    for (int off = 1; off < 64; off <<= 1) { s += __shfl_xor(s, off); s2 += __shfl_xor(s2, off); }
    __shared__ float sh[4];
    int wid = t >> 6, lane = t & 63;
    if (lane == 0) { sh[wid] = s; sh[2 + wid] = s2; }
    __syncthreads();
    float tot = sh[0] + sh[1], tot2 = sh[2] + sh[3];
    float mean = tot * (1.0f / CH);
    float var = tot2 * (1.0f / CH) - mean * mean;
    float rstd = rsqrtf(var + 1e-5f);
    float4 gv = ((const float4*)gamma)[t];
    float4 bv = ((const float4*)beta)[t];
    uint2 rv = ((const uint2*)(residb + (size_t)i * CH))[t];
    float y0 = (a0 - mean) * rstd * gv.x + bv.x; y0 = (y0 > 0.f ? y0 : __expf(y0) - 1.f) + bf2f(rv.x & 0xffff);
    float y1 = (a1 - mean) * rstd * gv.y + bv.y; y1 = (y1 > 0.f ? y1 : __expf(y1) - 1.f) + bf2f(rv.x >> 16);
    float y2 = (a2 - mean) * rstd * gv.z + bv.z; y2 = (y2 > 0.f ? y2 : __expf(y2) - 1.f) + bf2f(rv.y & 0xffff);
    float y3 = (a3 - mean) * rstd * gv.w + bv.w; y3 = (y3 > 0.f ? y3 : __expf(y3) - 1.f) + bf2f(rv.y >> 16);
    ushort4 o; o.x = f2bf(y0); o.y = f2bf(y1); o.z = f2bf(y2); o.w = f2bf(y3);
    ((ushort4*)(outb + (size_t)i * CH))[t] = o;
}

// ---------------- small GEMM: h3[M,16] = A[M,512](bf16) @ W3[512,16](fp32) ----------------
__global__ __launch_bounds__(256) void gemm_small_k(const ushort* __restrict__ A, const float* __restrict__ W,
                                                    float* __restrict__ C) {
    int col = threadIdx.x & 15;
    int row = blockIdx.x * 16 + (threadIdx.x >> 4);
    if (row >= NNODES) return;
    const ushort* ar = A + (size_t)row * CH;
    float acc = 0.f;
#pragma unroll 8
    for (int k = 0; k < CH; k += 2) {
        uint av = *(const uint*)(ar + k);
        acc += bf2f(av & 0xffff) * W[k * COUT + col];
        acc += bf2f(av >> 16) * W[(k + 1) * COUT + col];
    }
    C[row * COUT + col] = acc;
}

// -------- FUSED final layer: logits + two-pass softmax + gather + bias + LN (16 ch) --------
// 256 thr = 16 nodes x 16 ch; h3[src] row loaded once per pass
__global__ __launch_bounds__(256) void agg16f_k(const float* __restrict__ h3, const float* __restrict__ as3,
                                                const float* __restrict__ ad3, const int* __restrict__ startA,
                                                const int* __restrict__ deg, const int* __restrict__ csr,
                                                const float* __restrict__ b3, const float* __restrict__ g3,
                                                const float* __restrict__ be3, float* __restrict__ out) {
    int t = threadIdx.x;
    int i = blockIdx.x * 16 + (t >> 4);
    int c = t & 15;
    if (i >= NNODES) return;
    float asc = as3[c], adc = ad3[c];
    // ald_i = h3[i] . ad3  (width-16 shuffle reduce)
    float ald_i = h3[i * COUT + c] * adc;
#pragma unroll
    for (int off = 1; off < 16; off <<= 1) ald_i += __shfl_xor(ald_i, off, 16);
    int s0 = startA[i], d = deg[i];
    // pass 1: segment max (logit recomputed; h3 rows L2-resident at 640KB)
    float m = -1e30f;
    for (int e = 0; e < d; ++e) {
        int src = csr[s0 + e];
        float al = h3[src * COUT + c] * asc;
#pragma unroll
        for (int off = 1; off < 16; off <<= 1) al += __shfl_xor(al, off, 16);
        float ee = al + ald_i;
        ee = ee > 0.f ? ee : NEG_SLOPE * ee;
        m = fmaxf(m, ee);
    }
    // pass 2: independent weighted gather
    float ssum = 0.f, acc = 0.f;
    for (int e = 0; e < d; ++e) {
        int src = csr[s0 + e];
        float v = h3[src * COUT + c];
        float al = v * asc;
#pragma unroll
        for (int off = 1; off < 16; off <<= 1) al += __shfl_xor(al, off, 16);
        float ee = al + ald_i;
        ee = ee > 0.f ? ee : NEG_SLOPE * ee;
        float p = __expf(ee - m);
        ssum += p;
        acc += p * v;
    }
    acc = acc / (ssum + 1e-16f) + b3[c];
    float v = acc, v2 = acc * acc;
#pragma unroll
    for (int off = 1; off < 16; off <<= 1) { v += __shfl_xor(v, off, 16); v2 += __shfl_xor(v2, off, 16); }
    float mean = v * (1.0f / COUT);
    float var = v2 * (1.0f / COUT) - mean * mean;
    out[i * COUT + c] = (acc - mean) * rsqrtf(var + 1e-5f) * g3[c] + be3[c];
}

extern "C" void kernel_launch(void* const* d_in, const int* in_sizes, int n_in,
                              void* d_out, int out_size, void* d_ws, size_t ws_size,
                              hipStream_t stream) {
    const float* x   = (const float*)d_in[0];
    const int*   ei  = (const int*)d_in[1];
    const float* Wp  = (const float*)d_in[2];
    const float* bp  = (const float*)d_in[3];
    const float* g0  = (const float*)d_in[4];
    const float* b0  = (const float*)d_in[5];
    const float* W1  = (const float*)d_in[6];
    const float* as1 = (const float*)d_in[7];
    const float* ad1 = (const float*)d_in[8];
    const float* b1  = (const float*)d_in[9];
    const float* g1  = (const float*)d_in[10];
    const float* be1 = (const float*)d_in[11];
    const float* W2  = (const float*)d_in[12];
    const float* as2 = (const float*)d_in[13];
    const float* ad2 = (const float*)d_in[14];
    const float* b2  = (const float*)d_in[15];
    const float* g2  = (const float*)d_in[16];
    const float* be2 = (const float*)d_in[17];
    const float* W3  = (const float*)d_in[18];
    const float* as3 = (const float*)d_in[19];
    const float* ad3 = (const float*)d_in[20];
    const float* b3  = (const float*)d_in[21];
    const float* g3  = (const float*)d_in[22];
    const float* be3 = (const float*)d_in[23];

    // ---- workspace carve (~40 MB) ----
    ushort* B0  = (ushort*)d_ws;           // NF bf16 activations (rotating)
    ushort* B1  = B0 + NF;
    ushort* B2  = B1 + NF;
    ushort* xbf = B2 + NF;                 // NNODES*CIN
    ushort* Wpt = xbf + (size_t)NNODES * CIN;   // CIN*CH
    ushort* W1t = Wpt + (size_t)CIN * CH;       // CH*CH
    ushort* W2t = W1t + (size_t)CH * CH;
    float* als = (float*)(W2t + (size_t)CH * CH);
    float* ald = als + NNODES * NHEAD;
    float* h3  = ald + NNODES * NHEAD;          // NNODES*COUT
    int* deg = (int*)(h3 + (size_t)NNODES * COUT);
    int* stA = deg + NNODES;
    int* cur = stA + NNODES;
    int* csr = cur + NNODES;

    // ---- CSR build ----
    hipMemsetAsync(deg, 0, NNODES * sizeof(int), stream);
    hipMemsetAsync(cur, 0, NNODES * sizeof(int), stream);
    count_deg_k<<<(ETOT + 255) / 256, 256, 0, stream>>>(ei, deg);
    scan_k<<<1, 512, 0, stream>>>(deg, stA);
    scatter_k<<<(ETOT + 255) / 256, 256, 0, stream>>>(ei, stA, cur, csr);

    // ---- converts ----
    convert_x_k<<<(NNODES * CIN / 4 + 255) / 256, 256, 0, stream>>>(x, xbf);
    convert_wT_k<<<dim3(CH / 32, CIN / 32), 256, 0, stream>>>(Wp, Wpt, CIN, CH);
    convert_wT_k<<<dim3(CH / 32, CH / 32), 256, 0, stream>>>(W1, W1t, CH, CH);
    convert_wT_k<<<dim3(CH / 32, CH / 32), 256, 0, stream>>>(W2, W2t, CH, CH);

    dim3 gg((NNODES + 63) / 64, CH / 64);

    // ---- input projection + LN + ELU ----
    gemm_mfma<<<gg, 256, 0, stream>>>(xbf, Wpt, bp, B0, NNODES, CIN);
    ln_elu_k<<<NNODES, 128, 0, stream>>>(B0, g0, b0, B1);

    // ---- GAT layer 1: h=gemm(B1) -> B2; fused agg(resid=B1) -> B0 ----
    gemm_mfma<<<gg, 256, 0, stream>>>(B1, W1t, nullptr, B2, NNODES, CH);
    attn_logits_k<<<(NNODES * NHEAD + 255) / 256, 256, 0, stream>>>(B2, as1, ad1, als, ald);
    agg_ln_k<<<NNODES, 128, 0, stream>>>(B2, als, ald, stA, deg, csr, b1, g1, be1, B1, B0);

    // ---- GAT layer 2: h=gemm(B0) -> B1; fused agg(resid=B0) -> B2 ----
    gemm_mfma<<<gg, 256, 0, stream>>>(B0, W2t, nullptr, B1, NNODES, CH);
    attn_logits_k<<<(NNODES * NHEAD + 255) / 256, 256, 0, stream>>>(B1, as2, ad2, als, ald);
    agg_ln_k<<<NNODES, 128, 0, stream>>>(B1, als, ald, stA, deg, csr, b2, g2, be2, B0, B2);

    // ---- final layer (B2 -> d_out): small GEMM + fully fused attention ----
    gemm_small_k<<<(NNODES + 15) / 16, 256, 0, stream>>>(B2, W3, h3);
    agg16f_k<<<(NNODES + 15) / 16, 256, 0, stream>>>(h3, as3, ad3, stA, deg, csr, b3, g3, be3, (float*)d_out);
}

// Round 9
// 349.401 us; speedup vs baseline: 1.0528x; 1.0528x over previous
//
#include <hip/hip_runtime.h>
#include <hip/hip_bf16.h>

#define NNODES 10000
#define NEDGES 160000
#define ETOT   (NEDGES + NNODES)
#define CIN    256
#define CH     512     // HID*H
#define NHEAD  8
#define HDIM   64
#define COUT   16
#define NEG_SLOPE 0.2f
#define NF ((size_t)NNODES * CH)

// ---------- bf16 helpers ----------
__device__ __forceinline__ float bf2f(uint u) {
    union { uint i; float f; } v; v.i = u << 16; return v.f;
}
__device__ __forceinline__ ushort f2bf(float x) {
    union { float f; uint i; } v; v.f = x;
    uint r = v.i + 0x7fff + ((v.i >> 16) & 1);
    return (ushort)(r >> 16);
}

typedef __attribute__((ext_vector_type(8))) short short8v;
typedef __attribute__((ext_vector_type(4))) float f32x4;

// ---------------- CSR build ----------------
__global__ void count_deg_k(const int* __restrict__ ei, int* __restrict__ deg) {
    int eid = blockIdx.x * 256 + threadIdx.x;
    if (eid >= ETOT) return;
    int dst = (eid < NEDGES) ? ei[NEDGES + eid] : (eid - NEDGES);
    atomicAdd(&deg[dst], 1);
}

__global__ __launch_bounds__(512) void scan_k(const int* __restrict__ deg, int* __restrict__ startA) {
    __shared__ int partial[512];
    int t = threadIdx.x;
    const int per = (NNODES + 511) / 512;  // 20
    int base = t * per;
    int s = 0;
    for (int j = 0; j < per; ++j) { int idx = base + j; if (idx < NNODES) s += deg[idx]; }
    partial[t] = s;
    __syncthreads();
    for (int off = 1; off < 512; off <<= 1) {
        int v = (t >= off) ? partial[t - off] : 0;
        __syncthreads();
        partial[t] += v;
        __syncthreads();
    }
    int run = (t == 0) ? 0 : partial[t - 1];
    for (int j = 0; j < per; ++j) {
        int idx = base + j;
        if (idx < NNODES) { startA[idx] = run; run += deg[idx]; }
    }
}

__global__ void scatter_k(const int* __restrict__ ei, const int* __restrict__ startA,
                          int* __restrict__ cursor, int* __restrict__ csr_src) {
    int eid = blockIdx.x * 256 + threadIdx.x;
    if (eid >= ETOT) return;
    int src, dst;
    if (eid < NEDGES) { src = ei[eid]; dst = ei[NEDGES + eid]; }
    else { src = dst = eid - NEDGES; }
    int pos = startA[dst] + atomicAdd(&cursor[dst], 1);
    csr_src[pos] = src;
}

// ---------------- converts ----------------
__global__ void convert_x_k(const float* __restrict__ x, ushort* __restrict__ xb) {
    int idx = blockIdx.x * 256 + threadIdx.x;
    if (idx >= NNODES * CIN / 4) return;
    float4 v = ((const float4*)x)[idx];
    ushort4 o; o.x = f2bf(v.x); o.y = f2bf(v.y); o.z = f2bf(v.z); o.w = f2bf(v.w);
    ((ushort4*)xb)[idx] = o;
}

// W[K][N] fp32 -> Wt[N][K] bf16, 32x32 LDS tile transpose
__global__ __launch_bounds__(256) void convert_wT_k(const float* __restrict__ W, ushort* __restrict__ Wt,
                                                    int K, int N) {
    __shared__ float tile[32][33];
    int tx = threadIdx.x & 31, ty = threadIdx.x >> 5;  // 32x8
    int n0 = blockIdx.x * 32, k0 = blockIdx.y * 32;
#pragma unroll
    for (int r = 0; r < 32; r += 8)
        tile[ty + r][tx] = W[(size_t)(k0 + ty + r) * N + n0 + tx];
    __syncthreads();
#pragma unroll
    for (int r = 0; r < 32; r += 8)
        Wt[(size_t)(n0 + ty + r) * K + k0 + tx] = f2bf(tile[tx][ty + r]);
}

// ------- bf16 MFMA GEMM, BK=64, fused per-head logit epilogue --------------
// C[M,CH] = A[M,K] @ Bt[CH,K]^T (+bias). 64x64 tile, 4 waves (2x2), 8 MFMA/K-step.
// col-tile 64 == one head: if a_src!=null, block also emits als/ald for its rows.
#define LDB 72  // padded LDS row stride (bf16 elems)
__global__ __launch_bounds__(256) void gemm_mfma(const ushort* __restrict__ A, const ushort* __restrict__ Bt,
                                                 const float* __restrict__ bias, ushort* __restrict__ C,
                                                 const float* __restrict__ a_src, const float* __restrict__ a_dst,
                                                 float* __restrict__ als, float* __restrict__ ald,
                                                 int M, int K) {
    __shared__ ushort Asl[64 * LDB];
    __shared__ ushort Bsl[64 * LDB];
    __shared__ float lals[2][64], lald[2][64];
    int t = threadIdx.x;
    int wid = t >> 6, lane = t & 63;
    int row0 = blockIdx.x * 64, col0 = blockIdx.y * 64;
    int wr = (wid >> 1) * 32, wc = (wid & 1) * 32;
    f32x4 acc[2][2] = {};
    int sRow = t >> 2;          // 0..63
    int sK = (t & 3) * 16;      // 0,16,32,48
    int lr = lane & 15;
    int kg = lane >> 4;

    for (int k0 = 0; k0 < K; k0 += 64) {
        int gr = row0 + sRow;
        uint4 av0 = {0u,0u,0u,0u}, av1 = {0u,0u,0u,0u};
        if (gr < M) {
            const ushort* ap = A + (size_t)gr * K + k0 + sK;
            av0 = *(const uint4*)ap; av1 = *(const uint4*)(ap + 8);
        }
        *(uint4*)(&Asl[sRow * LDB + sK]) = av0;
        *(uint4*)(&Asl[sRow * LDB + sK + 8]) = av1;
        const ushort* bp = Bt + (size_t)(col0 + sRow) * K + k0 + sK;
        *(uint4*)(&Bsl[sRow * LDB + sK]) = *(const uint4*)bp;
        *(uint4*)(&Bsl[sRow * LDB + sK + 8]) = *(const uint4*)(bp + 8);
        __syncthreads();
#pragma unroll
        for (int ks = 0; ks < 2; ++ks) {
            short8v a0 = *(const short8v*)&Asl[(wr + lr) * LDB + ks * 32 + kg * 8];
            short8v a1 = *(const short8v*)&Asl[(wr + 16 + lr) * LDB + ks * 32 + kg * 8];
            short8v b0 = *(const short8v*)&Bsl[(wc + lr) * LDB + ks * 32 + kg * 8];
            short8v b1 = *(const short8v*)&Bsl[(wc + 16 + lr) * LDB + ks * 32 + kg * 8];
            acc[0][0] = __builtin_amdgcn_mfma_f32_16x16x32_bf16(a0, b0, acc[0][0], 0, 0, 0);
            acc[0][1] = __builtin_amdgcn_mfma_f32_16x16x32_bf16(a0, b1, acc[0][1], 0, 0, 0);
            acc[1][0] = __builtin_amdgcn_mfma_f32_16x16x32_bf16(a1, b0, acc[1][0], 0, 0, 0);
            acc[1][1] = __builtin_amdgcn_mfma_f32_16x16x32_bf16(a1, b1, acc[1][1], 0, 0, 0);
        }
        __syncthreads();
    }
    // C/D layout: col = lane&15, row = (lane>>4)*4 + q   [m89-verified]
    float pals[2][4] = {}, pald[2][4] = {};
    bool doLog = (a_src != nullptr);
    int head = blockIdx.y;
#pragma unroll
    for (int i = 0; i < 2; ++i) {
#pragma unroll
        for (int j = 0; j < 2; ++j) {
            int cl = wc + j * 16 + lr;           // local col 0..63
            int c = col0 + cl;
            float bb = bias ? bias[c] : 0.f;
            float as_c = doLog ? a_src[head * HDIM + cl] : 0.f;
            float ad_c = doLog ? a_dst[head * HDIM + cl] : 0.f;
#pragma unroll
            for (int q = 0; q < 4; ++q) {
                int r = row0 + wr + i * 16 + kg * 4 + q;
                float hv = acc[i][j][q] + bb;
                if (r < M) C[(size_t)r * CH + c] = f2bf(hv);
                pals[i][q] += hv * as_c;
                pald[i][q] += hv * ad_c;
            }
        }
    }
    if (doLog) {
        // reduce over lr (16 lanes) -> every lane has the 32-col partial for its rows
#pragma unroll
        for (int i = 0; i < 2; ++i)
#pragma unroll
            for (int q = 0; q < 4; ++q) {
#pragma unroll
                for (int off = 1; off < 16; off <<= 1) {
                    pals[i][q] += __shfl_xor(pals[i][q], off);
                    pald[i][q] += __shfl_xor(pald[i][q], off);
                }
            }
        if (lr == 0) {
#pragma unroll
            for (int i = 0; i < 2; ++i)
#pragma unroll
                for (int q = 0; q < 4; ++q) {
                    int r = wr + i * 16 + kg * 4 + q;   // 0..63
                    lals[wid & 1][r] = pals[i][q];
                    lald[wid & 1][r] = pald[i][q];
                }
        }
        __syncthreads();
        if (t < 64) {
            int r = row0 + t;
            if (r < M) {
                als[r * NHEAD + head] = lals[0][t] + lals[1][t];
                ald[r * NHEAD + head] = lald[0][t] + lald[1][t];
            }
        }
    }
}

// ---------------- LN + ELU on bf16 (128 thr, 4 ch/thread) ----------------
__global__ __launch_bounds__(128) void ln_elu_k(const ushort* __restrict__ inb, const float* __restrict__ g,
                                                const float* __restrict__ b, ushort* __restrict__ outb) {
    int i = blockIdx.x, t = threadIdx.x;
    uint2 hv = ((const uint2*)(inb + (size_t)i * CH))[t];
    float a0 = bf2f(hv.x & 0xffff), a1 = bf2f(hv.x >> 16);
    float a2 = bf2f(hv.y & 0xffff), a3 = bf2f(hv.y >> 16);
    float s = a0 + a1 + a2 + a3;
    float s2 = a0 * a0 + a1 * a1 + a2 * a2 + a3 * a3;
#pragma unroll
    for (int off = 1; off < 64; off <<= 1) { s += __shfl_xor(s, off); s2 += __shfl_xor(s2, off); }
    __shared__ float sh[4];
    int wid = t >> 6, lane = t & 63;
    if (lane == 0) { sh[wid] = s; sh[2 + wid] = s2; }
    __syncthreads();
    float tot = sh[0] + sh[1], tot2 = sh[2] + sh[3];
    float mean = tot * (1.0f / CH);
    float var = tot2 * (1.0f / CH) - mean * mean;
    float rstd = rsqrtf(var + 1e-5f);
    float4 gv = ((const float4*)g)[t];
    float4 bv = ((const float4*)b)[t];
    float y0 = (a0 - mean) * rstd * gv.x + bv.x; y0 = y0 > 0.f ? y0 : __expf(y0) - 1.f;
    float y1 = (a1 - mean) * rstd * gv.y + bv.y; y1 = y1 > 0.f ? y1 : __expf(y1) - 1.f;
    float y2 = (a2 - mean) * rstd * gv.z + bv.z; y2 = y2 > 0.f ? y2 : __expf(y2) - 1.f;
    float y3 = (a3 - mean) * rstd * gv.w + bv.w; y3 = y3 > 0.f ? y3 : __expf(y3) - 1.f;
    ushort4 o; o.x = f2bf(y0); o.y = f2bf(y1); o.z = f2bf(y2); o.w = f2bf(y3);
    ((ushort4*)(outb + (size_t)i * CH))[t] = o;
}

// -------- FUSED two-pass softmax gather + bias + LN + ELU + residual -----------
// 128 thr = 2 nodes x 64 thr; 8 ch/thread (uint4, 16B/lane); LN = pure wave-64 shuffle.
__global__ __launch_bounds__(128) void agg_ln_k(const ushort* __restrict__ hb, const float* __restrict__ als,
                                                const float* __restrict__ ald, const int* __restrict__ startA,
                                                const int* __restrict__ deg, const int* __restrict__ csr,
                                                const float* __restrict__ bias, const float* __restrict__ gamma,
                                                const float* __restrict__ beta, const ushort* __restrict__ residb,
                                                ushort* __restrict__ outb) {
    int t = threadIdx.x;
    int i = blockIdx.x * 2 + (t >> 6);
    int tl = t & 63;
    int c0 = tl * 8, head = tl >> 3;
    int s0 = startA[i], d = deg[i];
    float aldv = ald[i * NHEAD + head];
    const int* cp = csr + s0;
    // pass 1: segment max
    float m = -1e30f;
    for (int e = 0; e < d; ++e) {
        int src = cp[e];
        float ee = als[src * NHEAD + head] + aldv;
        ee = ee > 0.f ? ee : NEG_SLOPE * ee;
        m = fmaxf(m, ee);
    }
    // pass 2: independent weighted gather (16B/lane)
    float ssum = 0.f;
    float a0 = 0, a1 = 0, a2 = 0, a3 = 0, a4 = 0, a5 = 0, a6 = 0, a7 = 0;
    for (int e = 0; e < d; ++e) {
        int src = cp[e];
        float ee = als[src * NHEAD + head] + aldv;
        ee = ee > 0.f ? ee : NEG_SLOPE * ee;
        float p = __expf(ee - m);
        ssum += p;
        uint4 hv = *(const uint4*)(hb + (size_t)src * CH + c0);
        a0 += p * bf2f(hv.x & 0xffff); a1 += p * bf2f(hv.x >> 16);
        a2 += p * bf2f(hv.y & 0xffff); a3 += p * bf2f(hv.y >> 16);
        a4 += p * bf2f(hv.z & 0xffff); a5 += p * bf2f(hv.z >> 16);
        a6 += p * bf2f(hv.w & 0xffff); a7 += p * bf2f(hv.w >> 16);
    }
    float inv = 1.0f / (ssum + 1e-16f);
    float4 bi0 = ((const float4*)bias)[tl * 2], bi1 = ((const float4*)bias)[tl * 2 + 1];
    a0 = a0 * inv + bi0.x; a1 = a1 * inv + bi0.y; a2 = a2 * inv + bi0.z; a3 = a3 * inv + bi0.w;
    a4 = a4 * inv + bi1.x; a5 = a5 * inv + bi1.y; a6 = a6 * inv + bi1.z; a7 = a7 * inv + bi1.w;
    float s = a0 + a1 + a2 + a3 + a4 + a5 + a6 + a7;
    float s2 = a0*a0 + a1*a1 + a2*a2 + a3*a3 + a4*a4 + a5*a5 + a6*a6 + a7*a7;
#pragma unroll
    for (int off = 1; off < 64; off <<= 1) { s += __shfl_xor(s, off); s2 += __shfl_xor(s2, off); }
    float mean = s * (1.0f / CH);
    float var = s2 * (1.0f / CH) - mean * mean;
    float rstd = rsqrtf(var + 1e-5f);
    float4 gv0 = ((const float4*)gamma)[tl * 2], gv1 = ((const float4*)gamma)[tl * 2 + 1];
    float4 bv0 = ((const float4*)beta)[tl * 2],  bv1 = ((const float4*)beta)[tl * 2 + 1];
    uint4 rv = ((const uint4*)(residb + (size_t)i * CH))[tl];
    float y0 = (a0 - mean) * rstd * gv0.x + bv0.x; y0 = (y0 > 0.f ? y0 : __expf(y0) - 1.f) + bf2f(rv.x & 0xffff);
    float y1 = (a1 - mean) * rstd * gv0.y + bv0.y; y1 = (y1 > 0.f ? y1 : __expf(y1) - 1.f) + bf2f(rv.x >> 16);
    float y2 = (a2 - mean) * rstd * gv0.z + bv0.z; y2 = (y2 > 0.f ? y2 : __expf(y2) - 1.f) + bf2f(rv.y & 0xffff);
    float y3 = (a3 - mean) * rstd * gv0.w + bv0.w; y3 = (y3 > 0.f ? y3 : __expf(y3) - 1.f) + bf2f(rv.y >> 16);
    float y4 = (a4 - mean) * rstd * gv1.x + bv1.x; y4 = (y4 > 0.f ? y4 : __expf(y4) - 1.f) + bf2f(rv.z & 0xffff);
    float y5 = (a5 - mean) * rstd * gv1.y + bv1.y; y5 = (y5 > 0.f ? y5 : __expf(y5) - 1.f) + bf2f(rv.z >> 16);
    float y6 = (a6 - mean) * rstd * gv1.z + bv1.z; y6 = (y6 > 0.f ? y6 : __expf(y6) - 1.f) + bf2f(rv.w & 0xffff);
    float y7 = (a7 - mean) * rstd * gv1.w + bv1.w; y7 = (y7 > 0.f ? y7 : __expf(y7) - 1.f) + bf2f(rv.w >> 16);
    uint4 o;
    o.x = (uint)f2bf(y0) | ((uint)f2bf(y1) << 16);
    o.y = (uint)f2bf(y2) | ((uint)f2bf(y3) << 16);
    o.z = (uint)f2bf(y4) | ((uint)f2bf(y5) << 16);
    o.w = (uint)f2bf(y6) | ((uint)f2bf(y7) << 16);
    ((uint4*)(outb + (size_t)i * CH))[tl] = o;
}

// ---------------- small GEMM: h3[M,16] = A[M,512](bf16) @ W3[512,16](fp32) ----------------
__global__ __launch_bounds__(256) void gemm_small_k(const ushort* __restrict__ A, const float* __restrict__ W,
                                                    float* __restrict__ C) {
    int col = threadIdx.x & 15;
    int row = blockIdx.x * 16 + (threadIdx.x >> 4);
    if (row >= NNODES) return;
    const ushort* ar = A + (size_t)row * CH;
    float acc = 0.f;
#pragma unroll 8
    for (int k = 0; k < CH; k += 2) {
        uint av = *(const uint*)(ar + k);
        acc += bf2f(av & 0xffff) * W[k * COUT + col];
        acc += bf2f(av >> 16) * W[(k + 1) * COUT + col];
    }
    C[row * COUT + col] = acc;
}

// -------- FUSED final layer: logits + two-pass softmax + gather + bias + LN (16 ch) --------
__global__ __launch_bounds__(256) void agg16f_k(const float* __restrict__ h3, const float* __restrict__ as3,
                                                const float* __restrict__ ad3, const int* __restrict__ startA,
                                                const int* __restrict__ deg, const int* __restrict__ csr,
                                                const float* __restrict__ b3, const float* __restrict__ g3,
                                                const float* __restrict__ be3, float* __restrict__ out) {
    int t = threadIdx.x;
    int i = blockIdx.x * 16 + (t >> 4);
    int c = t & 15;
    if (i >= NNODES) return;
    float asc = as3[c], adc = ad3[c];
    float ald_i = h3[i * COUT + c] * adc;
#pragma unroll
    for (int off = 1; off < 16; off <<= 1) ald_i += __shfl_xor(ald_i, off, 16);
    int s0 = startA[i], d = deg[i];
    float m = -1e30f;
    for (int e = 0; e < d; ++e) {
        int src = csr[s0 + e];
        float al = h3[src * COUT + c] * asc;
#pragma unroll
        for (int off = 1; off < 16; off <<= 1) al += __shfl_xor(al, off, 16);
        float ee = al + ald_i;
        ee = ee > 0.f ? ee : NEG_SLOPE * ee;
        m = fmaxf(m, ee);
    }
    float ssum = 0.f, acc = 0.f;
    for (int e = 0; e < d; ++e) {
        int src = csr[s0 + e];
        float v = h3[src * COUT + c];
        float al = v * asc;
#pragma unroll
        for (int off = 1; off < 16; off <<= 1) al += __shfl_xor(al, off, 16);
        float ee = al + ald_i;
        ee = ee > 0.f ? ee : NEG_SLOPE * ee;
        float p = __expf(ee - m);
        ssum += p;
        acc += p * v;
    }
    acc = acc / (ssum + 1e-16f) + b3[c];
    float v = acc, v2 = acc * acc;
#pragma unroll
    for (int off = 1; off < 16; off <<= 1) { v += __shfl_xor(v, off, 16); v2 += __shfl_xor(v2, off, 16); }
    float mean = v * (1.0f / COUT);
    float var = v2 * (1.0f / COUT) - mean * mean;
    out[i * COUT + c] = (acc - mean) * rsqrtf(var + 1e-5f) * g3[c] + be3[c];
}

extern "C" void kernel_launch(void* const* d_in, const int* in_sizes, int n_in,
                              void* d_out, int out_size, void* d_ws, size_t ws_size,
                              hipStream_t stream) {
    const float* x   = (const float*)d_in[0];
    const int*   ei  = (const int*)d_in[1];
    const float* Wp  = (const float*)d_in[2];
    const float* bp  = (const float*)d_in[3];
    const float* g0  = (const float*)d_in[4];
    const float* b0  = (const float*)d_in[5];
    const float* W1  = (const float*)d_in[6];
    const float* as1 = (const float*)d_in[7];
    const float* ad1 = (const float*)d_in[8];
    const float* b1  = (const float*)d_in[9];
    const float* g1  = (const float*)d_in[10];
    const float* be1 = (const float*)d_in[11];
    const float* W2  = (const float*)d_in[12];
    const float* as2 = (const float*)d_in[13];
    const float* ad2 = (const float*)d_in[14];
    const float* b2  = (const float*)d_in[15];
    const float* g2  = (const float*)d_in[16];
    const float* be2 = (const float*)d_in[17];
    const float* W3  = (const float*)d_in[18];
    const float* as3 = (const float*)d_in[19];
    const float* ad3 = (const float*)d_in[20];
    const float* b3  = (const float*)d_in[21];
    const float* g3  = (const float*)d_in[22];
    const float* be3 = (const float*)d_in[23];

    // ---- workspace carve (~40 MB) ----
    ushort* B0  = (ushort*)d_ws;
    ushort* B1  = B0 + NF;
    ushort* B2  = B1 + NF;
    ushort* xbf = B2 + NF;                 // NNODES*CIN
    ushort* Wpt = xbf + (size_t)NNODES * CIN;   // CIN*CH
    ushort* W1t = Wpt + (size_t)CIN * CH;       // CH*CH
    ushort* W2t = W1t + (size_t)CH * CH;
    float* als = (float*)(W2t + (size_t)CH * CH);
    float* ald = als + NNODES * NHEAD;
    float* h3  = ald + NNODES * NHEAD;          // NNODES*COUT
    int* deg = (int*)(h3 + (size_t)NNODES * COUT);
    int* stA = deg + NNODES;
    int* cur = stA + NNODES;
    int* csr = cur + NNODES;

    // ---- CSR build ----
    hipMemsetAsync(deg, 0, NNODES * sizeof(int), stream);
    hipMemsetAsync(cur, 0, NNODES * sizeof(int), stream);
    count_deg_k<<<(ETOT + 255) / 256, 256, 0, stream>>>(ei, deg);
    scan_k<<<1, 512, 0, stream>>>(deg, stA);
    scatter_k<<<(ETOT + 255) / 256, 256, 0, stream>>>(ei, stA, cur, csr);

    // ---- converts ----
    convert_x_k<<<(NNODES * CIN / 4 + 255) / 256, 256, 0, stream>>>(x, xbf);
    convert_wT_k<<<dim3(CH / 32, CIN / 32), 256, 0, stream>>>(Wp, Wpt, CIN, CH);
    convert_wT_k<<<dim3(CH / 32, CH / 32), 256, 0, stream>>>(W1, W1t, CH, CH);
    convert_wT_k<<<dim3(CH / 32, CH / 32), 256, 0, stream>>>(W2, W2t, CH, CH);

    dim3 gg((NNODES + 63) / 64, CH / 64);

    // ---- input projection + LN + ELU ----
    gemm_mfma<<<gg, 256, 0, stream>>>(xbf, Wpt, bp, B0, nullptr, nullptr, nullptr, nullptr, NNODES, CIN);
    ln_elu_k<<<NNODES, 128, 0, stream>>>(B0, g0, b0, B1);

    // ---- GAT layer 1: h=gemm(B1)+logits -> B2,als,ald; fused agg(resid=B1) -> B0 ----
    gemm_mfma<<<gg, 256, 0, stream>>>(B1, W1t, nullptr, B2, as1, ad1, als, ald, NNODES, CH);
    agg_ln_k<<<NNODES / 2, 128, 0, stream>>>(B2, als, ald, stA, deg, csr, b1, g1, be1, B1, B0);

    // ---- GAT layer 2: h=gemm(B0)+logits -> B1,als,ald; fused agg(resid=B0) -> B2 ----
    gemm_mfma<<<gg, 256, 0, stream>>>(B0, W2t, nullptr, B1, as2, ad2, als, ald, NNODES, CH);
    agg_ln_k<<<NNODES / 2, 128, 0, stream>>>(B1, als, ald, stA, deg, csr, b2, g2, be2, B0, B2);

    // ---- final layer (B2 -> d_out): small GEMM + fully fused attention ----
    gemm_small_k<<<(NNODES + 15) / 16, 256, 0, stream>>>(B2, W3, h3);
    agg16f_k<<<(NNODES + 15) / 16, 256, 0, stream>>>(h3, as3, ad3, stA, deg, csr, b3, g3, be3, (float*)d_out);
}

// Round 11
// 343.180 us; speedup vs baseline: 1.0719x; 1.0181x over previous
//
#include <hip/hip_runtime.h>
#include <hip/hip_bf16.h>

#define NNODES 10000
#define NEDGES 160000
#define ETOT   (NEDGES + NNODES)
#define CIN    256
#define CH     512     // HID*H
#define NHEAD  8
#define HDIM   64
#define COUT   16
#define NEG_SLOPE 0.2f
#define NF ((size_t)NNODES * CH)

// ---------- bf16 helpers ----------
__device__ __forceinline__ float bf2f(uint u) {
    union { uint i; float f; } v; v.i = u << 16; return v.f;
}
__device__ __forceinline__ ushort f2bf(float x) {
    union { float f; uint i; } v; v.f = x;
    uint r = v.i + 0x7fff + ((v.i >> 16) & 1);
    return (ushort)(r >> 16);
}

typedef __attribute__((ext_vector_type(8))) short short8v;
typedef __attribute__((ext_vector_type(4))) float f32x4;

// ---------------- CSR build ----------------
__global__ void count_deg_k(const int* __restrict__ ei, int* __restrict__ deg) {
    int eid = blockIdx.x * 256 + threadIdx.x;
    if (eid >= ETOT) return;
    int dst = (eid < NEDGES) ? ei[NEDGES + eid] : (eid - NEDGES);
    atomicAdd(&deg[dst], 1);
}

__global__ __launch_bounds__(512) void scan_k(const int* __restrict__ deg, int* __restrict__ startA) {
    __shared__ int partial[512];
    int t = threadIdx.x;
    const int per = (NNODES + 511) / 512;  // 20
    int base = t * per;
    int s = 0;
    for (int j = 0; j < per; ++j) { int idx = base + j; if (idx < NNODES) s += deg[idx]; }
    partial[t] = s;
    __syncthreads();
    for (int off = 1; off < 512; off <<= 1) {
        int v = (t >= off) ? partial[t - off] : 0;
        __syncthreads();
        partial[t] += v;
        __syncthreads();
    }
    int run = (t == 0) ? 0 : partial[t - 1];
    for (int j = 0; j < per; ++j) {
        int idx = base + j;
        if (idx < NNODES) { startA[idx] = run; run += deg[idx]; }
    }
}

__global__ void scatter_k(const int* __restrict__ ei, const int* __restrict__ startA,
                          int* __restrict__ cursor, int* __restrict__ csr_src) {
    int eid = blockIdx.x * 256 + threadIdx.x;
    if (eid >= ETOT) return;
    int src, dst;
    if (eid < NEDGES) { src = ei[eid]; dst = ei[NEDGES + eid]; }
    else { src = dst = eid - NEDGES; }
    int pos = startA[dst] + atomicAdd(&cursor[dst], 1);
    csr_src[pos] = src;
}

// ---------------- converts ----------------
__global__ void convert_x_k(const float* __restrict__ x, ushort* __restrict__ xb) {
    int idx = blockIdx.x * 256 + threadIdx.x;
    if (idx >= NNODES * CIN / 4) return;
    float4 v = ((const float4*)x)[idx];
    ushort4 o; o.x = f2bf(v.x); o.y = f2bf(v.y); o.z = f2bf(v.z); o.w = f2bf(v.w);
    ((ushort4*)xb)[idx] = o;
}

// W[K][N] fp32 -> Wt[N][K] bf16, 32x32 LDS tile transpose
__global__ __launch_bounds__(256) void convert_wT_k(const float* __restrict__ W, ushort* __restrict__ Wt,
                                                    int K, int N) {
    __shared__ float tile[32][33];
    int tx = threadIdx.x & 31, ty = threadIdx.x >> 5;  // 32x8
    int n0 = blockIdx.x * 32, k0 = blockIdx.y * 32;
#pragma unroll
    for (int r = 0; r < 32; r += 8)
        tile[ty + r][tx] = W[(size_t)(k0 + ty + r) * N + n0 + tx];
    __syncthreads();
#pragma unroll
    for (int r = 0; r < 32; r += 8)
        Wt[(size_t)(n0 + ty + r) * K + k0 + tx] = f2bf(tile[tx][ty + r]);
}

// ------- bf16 MFMA GEMM, BK=64, fused per-head logit epilogue --------------
// C[M,CH] = A[M,K] @ Bt[CH,K]^T (+bias). 64x64 tile, 4 waves (2x2), 8 MFMA/K-step.
// col-tile 64 == one head: if a_src!=null, block also emits als/ald for its rows.
#define LDB 72  // padded LDS row stride (bf16 elems)
__global__ __launch_bounds__(256) void gemm_mfma(const ushort* __restrict__ A, const ushort* __restrict__ Bt,
                                                 const float* __restrict__ bias, ushort* __restrict__ C,
                                                 const float* __restrict__ a_src, const float* __restrict__ a_dst,
                                                 float* __restrict__ als, float* __restrict__ ald,
                                                 int M, int K) {
    __shared__ ushort Asl[64 * LDB];
    __shared__ ushort Bsl[64 * LDB];
    __shared__ float lals[2][64], lald[2][64];
    int t = threadIdx.x;
    int wid = t >> 6, lane = t & 63;
    int row0 = blockIdx.x * 64, col0 = blockIdx.y * 64;
    int wr = (wid >> 1) * 32, wc = (wid & 1) * 32;
    f32x4 acc[2][2] = {};
    int sRow = t >> 2;          // 0..63
    int sK = (t & 3) * 16;      // 0,16,32,48
    int lr = lane & 15;
    int kg = lane >> 4;

    for (int k0 = 0; k0 < K; k0 += 64) {
        int gr = row0 + sRow;
        uint4 av0 = {0u,0u,0u,0u}, av1 = {0u,0u,0u,0u};
        if (gr < M) {
            const ushort* ap = A + (size_t)gr * K + k0 + sK;
            av0 = *(const uint4*)ap; av1 = *(const uint4*)(ap + 8);
        }
        *(uint4*)(&Asl[sRow * LDB + sK]) = av0;
        *(uint4*)(&Asl[sRow * LDB + sK + 8]) = av1;
        const ushort* bp = Bt + (size_t)(col0 + sRow) * K + k0 + sK;
        *(uint4*)(&Bsl[sRow * LDB + sK]) = *(const uint4*)bp;
        *(uint4*)(&Bsl[sRow * LDB + sK + 8]) = *(const uint4*)(bp + 8);
        __syncthreads();
#pragma unroll
        for (int ks = 0; ks < 2; ++ks) {
            short8v a0 = *(const short8v*)&Asl[(wr + lr) * LDB + ks * 32 + kg * 8];
            short8v a1 = *(const short8v*)&Asl[(wr + 16 + lr) * LDB + ks * 32 + kg * 8];
            short8v b0 = *(const short8v*)&Bsl[(wc + lr) * LDB + ks * 32 + kg * 8];
            short8v b1 = *(const short8v*)&Bsl[(wc + 16 + lr) * LDB + ks * 32 + kg * 8];
            acc[0][0] = __builtin_amdgcn_mfma_f32_16x16x32_bf16(a0, b0, acc[0][0], 0, 0, 0);
            acc[0][1] = __builtin_amdgcn_mfma_f32_16x16x32_bf16(a0, b1, acc[0][1], 0, 0, 0);
            acc[1][0] = __builtin_amdgcn_mfma_f32_16x16x32_bf16(a1, b0, acc[1][0], 0, 0, 0);
            acc[1][1] = __builtin_amdgcn_mfma_f32_16x16x32_bf16(a1, b1, acc[1][1], 0, 0, 0);
        }
        __syncthreads();
    }
    // C/D layout: col = lane&15, row = (lane>>4)*4 + q   [m89-verified]
    float pals[2][4] = {}, pald[2][4] = {};
    bool doLog = (a_src != nullptr);
    int head = blockIdx.y;
#pragma unroll
    for (int i = 0; i < 2; ++i) {
#pragma unroll
        for (int j = 0; j < 2; ++j) {
            int cl = wc + j * 16 + lr;           // local col 0..63
            int c = col0 + cl;
            float bb = bias ? bias[c] : 0.f;
            float as_c = doLog ? a_src[head * HDIM + cl] : 0.f;
            float ad_c = doLog ? a_dst[head * HDIM + cl] : 0.f;
#pragma unroll
            for (int q = 0; q < 4; ++q) {
                int r = row0 + wr + i * 16 + kg * 4 + q;
                float hv = acc[i][j][q] + bb;
                if (r < M) C[(size_t)r * CH + c] = f2bf(hv);
                pals[i][q] += hv * as_c;
                pald[i][q] += hv * ad_c;
            }
        }
    }
    if (doLog) {
#pragma unroll
        for (int i = 0; i < 2; ++i)
#pragma unroll
            for (int q = 0; q < 4; ++q) {
#pragma unroll
                for (int off = 1; off < 16; off <<= 1) {
                    pals[i][q] += __shfl_xor(pals[i][q], off);
                    pald[i][q] += __shfl_xor(pald[i][q], off);
                }
            }
        if (lr == 0) {
#pragma unroll
            for (int i = 0; i < 2; ++i)
#pragma unroll
                for (int q = 0; q < 4; ++q) {
                    int r = wr + i * 16 + kg * 4 + q;   // 0..63
                    lals[wid & 1][r] = pals[i][q];
                    lald[wid & 1][r] = pald[i][q];
                }
        }
        __syncthreads();
        if (t < 64) {
            int r = row0 + t;
            if (r < M) {
                als[r * NHEAD + head] = lals[0][t] + lals[1][t];
                ald[r * NHEAD + head] = lald[0][t] + lald[1][t];
            }
        }
    }
}

// ---------------- LN + ELU on bf16 (128 thr, 4 ch/thread) ----------------
__global__ __launch_bounds__(128) void ln_elu_k(const ushort* __restrict__ inb, const float* __restrict__ g,
                                                const float* __restrict__ b, ushort* __restrict__ outb) {
    int i = blockIdx.x, t = threadIdx.x;
    uint2 hv = ((const uint2*)(inb + (size_t)i * CH))[t];
    float a0 = bf2f(hv.x & 0xffff), a1 = bf2f(hv.x >> 16);
    float a2 = bf2f(hv.y & 0xffff), a3 = bf2f(hv.y >> 16);
    float s = a0 + a1 + a2 + a3;
    float s2 = a0 * a0 + a1 * a1 + a2 * a2 + a3 * a3;
#pragma unroll
    for (int off = 1; off < 64; off <<= 1) { s += __shfl_xor(s, off); s2 += __shfl_xor(s2, off); }
    __shared__ float sh[4];
    int wid = t >> 6, lane = t & 63;
    if (lane == 0) { sh[wid] = s; sh[2 + wid] = s2; }
    __syncthreads();
    float tot = sh[0] + sh[1], tot2 = sh[2] + sh[3];
    float mean = tot * (1.0f / CH);
    float var = tot2 * (1.0f / CH) - mean * mean;
    float rstd = rsqrtf(var + 1e-5f);
    float4 gv = ((const float4*)g)[t];
    float4 bv = ((const float4*)b)[t];
    float y0 = (a0 - mean) * rstd * gv.x + bv.x; y0 = y0 > 0.f ? y0 : __expf(y0) - 1.f;
    float y1 = (a1 - mean) * rstd * gv.y + bv.y; y1 = y1 > 0.f ? y1 : __expf(y1) - 1.f;
    float y2 = (a2 - mean) * rstd * gv.z + bv.z; y2 = y2 > 0.f ? y2 : __expf(y2) - 1.f;
    float y3 = (a3 - mean) * rstd * gv.w + bv.w; y3 = y3 > 0.f ? y3 : __expf(y3) - 1.f;
    ushort4 o; o.x = f2bf(y0); o.y = f2bf(y1); o.z = f2bf(y2); o.w = f2bf(y3);
    ((ushort4*)(outb + (size_t)i * CH))[t] = o;
}

// -------- FUSED two-pass softmax gather + bias + LN + ELU + residual -----------
// 256 thr = 4 waves per ONE node; edges strided across waves (4x MLP).
// Lane tl covers channels tl*8..tl*8+7 (uint4 16B); head = tl>>3.
__global__ __launch_bounds__(256) void agg_ln_k(const ushort* __restrict__ hb, const float* __restrict__ als,
                                                const float* __restrict__ ald, const int* __restrict__ startA,
                                                const int* __restrict__ deg, const int* __restrict__ csr,
                                                const float* __restrict__ bias, const float* __restrict__ gamma,
                                                const float* __restrict__ beta, const ushort* __restrict__ residb,
                                                ushort* __restrict__ outb) {
    __shared__ float mws[4][8];
    __shared__ float sws[4][8];
    __shared__ float accb[4][8][64];   // [wave][chan-in-lane][lane] - column access, conflict-free
    int t = threadIdx.x;
    int w = t >> 6, tl = t & 63;
    int i = blockIdx.x;
    int c0 = tl * 8, head = tl >> 3;
    int s0 = startA[i], d = deg[i];
    float aldv = ald[i * NHEAD + head];
    const int* cp = csr + s0;
    // pass 1: per-wave segment max over strided edges
    float m = -1e30f;
    for (int e = w; e < d; e += 4) {
        int src = cp[e];
        float ee = als[src * NHEAD + head] + aldv;
        ee = ee > 0.f ? ee : NEG_SLOPE * ee;
        m = fmaxf(m, ee);
    }
    if ((tl & 7) == 0) mws[w][head] = m;
    __syncthreads();
    m = fmaxf(fmaxf(mws[0][head], mws[1][head]), fmaxf(mws[2][head], mws[3][head]));
    // pass 2: per-wave partial weighted gather (independent iterations)
    float ssum = 0.f;
    float a0 = 0, a1 = 0, a2 = 0, a3 = 0, a4 = 0, a5 = 0, a6 = 0, a7 = 0;
    for (int e = w; e < d; e += 4) {
        int src = cp[e];
        float ee = als[src * NHEAD + head] + aldv;
        ee = ee > 0.f ? ee : NEG_SLOPE * ee;
        float p = __expf(ee - m);
        ssum += p;
        uint4 hv = *(const uint4*)(hb + (size_t)src * CH + c0);
        a0 += p * bf2f(hv.x & 0xffff); a1 += p * bf2f(hv.x >> 16);
        a2 += p * bf2f(hv.y & 0xffff); a3 += p * bf2f(hv.y >> 16);
        a4 += p * bf2f(hv.z & 0xffff); a5 += p * bf2f(hv.z >> 16);
        a6 += p * bf2f(hv.w & 0xffff); a7 += p * bf2f(hv.w >> 16);
    }
    if ((tl & 7) == 0) sws[w][head] = ssum;
    accb[w][0][tl] = a0; accb[w][1][tl] = a1; accb[w][2][tl] = a2; accb[w][3][tl] = a3;
    accb[w][4][tl] = a4; accb[w][5][tl] = a5; accb[w][6][tl] = a6; accb[w][7][tl] = a7;
    __syncthreads();
    // combine across waves (all waves compute redundantly; wave 0 stores)
    ssum = sws[0][head] + sws[1][head] + sws[2][head] + sws[3][head];
    a0 = accb[0][0][tl] + accb[1][0][tl] + accb[2][0][tl] + accb[3][0][tl];
    a1 = accb[0][1][tl] + accb[1][1][tl] + accb[2][1][tl] + accb[3][1][tl];
    a2 = accb[0][2][tl] + accb[1][2][tl] + accb[2][2][tl] + accb[3][2][tl];
    a3 = accb[0][3][tl] + accb[1][3][tl] + accb[2][3][tl] + accb[3][3][tl];
    a4 = accb[0][4][tl] + accb[1][4][tl] + accb[2][4][tl] + accb[3][4][tl];
    a5 = accb[0][5][tl] + accb[1][5][tl] + accb[2][5][tl] + accb[3][5][tl];
    a6 = accb[0][6][tl] + accb[1][6][tl] + accb[2][6][tl] + accb[3][6][tl];
    a7 = accb[0][7][tl] + accb[1][7][tl] + accb[2][7][tl] + accb[3][7][tl];
    float inv = 1.0f / (ssum + 1e-16f);
    float4 bi0 = ((const float4*)bias)[tl * 2], bi1 = ((const float4*)bias)[tl * 2 + 1];
    a0 = a0 * inv + bi0.x; a1 = a1 * inv + bi0.y; a2 = a2 * inv + bi0.z; a3 = a3 * inv + bi0.w;
    a4 = a4 * inv + bi1.x; a5 = a5 * inv + bi1.y; a6 = a6 * inv + bi1.z; a7 = a7 * inv + bi1.w;
    float s = a0 + a1 + a2 + a3 + a4 + a5 + a6 + a7;
    float s2 = a0*a0 + a1*a1 + a2*a2 + a3*a3 + a4*a4 + a5*a5 + a6*a6 + a7*a7;
#pragma unroll
    for (int off = 1; off < 64; off <<= 1) { s += __shfl_xor(s, off); s2 += __shfl_xor(s2, off); }
    if (w != 0) return;
    float mean = s * (1.0f / CH);
    float var = s2 * (1.0f / CH) - mean * mean;
    float rstd = rsqrtf(var + 1e-5f);
    float4 gv0 = ((const float4*)gamma)[tl * 2], gv1 = ((const float4*)gamma)[tl * 2 + 1];
    float4 bv0 = ((const float4*)beta)[tl * 2],  bv1 = ((const float4*)beta)[tl * 2 + 1];
    uint4 rv = ((const uint4*)(residb + (size_t)i * CH))[tl];
    float y0 = (a0 - mean) * rstd * gv0.x + bv0.x; y0 = (y0 > 0.f ? y0 : __expf(y0) - 1.f) + bf2f(rv.x & 0xffff);
    float y1 = (a1 - mean) * rstd * gv0.y + bv0.y; y1 = (y1 > 0.f ? y1 : __expf(y1) - 1.f) + bf2f(rv.x >> 16);
    float y2 = (a2 - mean) * rstd * gv0.z + bv0.z; y2 = (y2 > 0.f ? y2 : __expf(y2) - 1.f) + bf2f(rv.y & 0xffff);
    float y3 = (a3 - mean) * rstd * gv0.w + bv0.w; y3 = (y3 > 0.f ? y3 : __expf(y3) - 1.f) + bf2f(rv.y >> 16);
    float y4 = (a4 - mean) * rstd * gv1.x + bv1.x; y4 = (y4 > 0.f ? y4 : __expf(y4) - 1.f) + bf2f(rv.z & 0xffff);
    float y5 = (a5 - mean) * rstd * gv1.y + bv1.y; y5 = (y5 > 0.f ? y5 : __expf(y5) - 1.f) + bf2f(rv.z >> 16);
    float y6 = (a6 - mean) * rstd * gv1.z + bv1.z; y6 = (y6 > 0.f ? y6 : __expf(y6) - 1.f) + bf2f(rv.w & 0xffff);
    float y7 = (a7 - mean) * rstd * gv1.w + bv1.w; y7 = (y7 > 0.f ? y7 : __expf(y7) - 1.f) + bf2f(rv.w >> 16);
    uint4 o;
    o.x = (uint)f2bf(y0) | ((uint)f2bf(y1) << 16);
    o.y = (uint)f2bf(y2) | ((uint)f2bf(y3) << 16);
    o.z = (uint)f2bf(y4) | ((uint)f2bf(y5) << 16);
    o.w = (uint)f2bf(y6) | ((uint)f2bf(y7) << 16);
    ((uint4*)(outb + (size_t)i * CH))[tl] = o;
}

// ---------------- small GEMM: h3[M,16] = A[M,512](bf16) @ W3[512,16](fp32) ----------------
__global__ __launch_bounds__(256) void gemm_small_k(const ushort* __restrict__ A, const float* __restrict__ W,
                                                    float* __restrict__ C) {
    int col = threadIdx.x & 15;
    int row = blockIdx.x * 16 + (threadIdx.x >> 4);
    if (row >= NNODES) return;
    const ushort* ar = A + (size_t)row * CH;
    float acc = 0.f;
#pragma unroll 8
    for (int k = 0; k < CH; k += 2) {
        uint av = *(const uint*)(ar + k);
        acc += bf2f(av & 0xffff) * W[k * COUT + col];
        acc += bf2f(av >> 16) * W[(k + 1) * COUT + col];
    }
    C[row * COUT + col] = acc;
}

// -------- FUSED final layer: logits + two-pass softmax + gather + bias + LN (16 ch) --------
__global__ __launch_bounds__(256) void agg16f_k(const float* __restrict__ h3, const float* __restrict__ as3,
                                                const float* __restrict__ ad3, const int* __restrict__ startA,
                                                const int* __restrict__ deg, const int* __restrict__ csr,
                                                const float* __restrict__ b3, const float* __restrict__ g3,
                                                const float* __restrict__ be3, float* __restrict__ out) {
    int t = threadIdx.x;
    int i = blockIdx.x * 16 + (t >> 4);
    int c = t & 15;
    if (i >= NNODES) return;
    float asc = as3[c], adc = ad3[c];
    float ald_i = h3[i * COUT + c] * adc;
#pragma unroll
    for (int off = 1; off < 16; off <<= 1) ald_i += __shfl_xor(ald_i, off, 16);
    int s0 = startA[i], d = deg[i];
    float m = -1e30f;
    for (int e = 0; e < d; ++e) {
        int src = csr[s0 + e];
        float al = h3[src * COUT + c] * asc;
#pragma unroll
        for (int off = 1; off < 16; off <<= 1) al += __shfl_xor(al, off, 16);
        float ee = al + ald_i;
        ee = ee > 0.f ? ee : NEG_SLOPE * ee;
        m = fmaxf(m, ee);
    }
    float ssum = 0.f, acc = 0.f;
    for (int e = 0; e < d; ++e) {
        int src = csr[s0 + e];
        float v = h3[src * COUT + c];
        float al = v * asc;
#pragma unroll
        for (int off = 1; off < 16; off <<= 1) al += __shfl_xor(al, off, 16);
        float ee = al + ald_i;
        ee = ee > 0.f ? ee : NEG_SLOPE * ee;
        float p = __expf(ee - m);
        ssum += p;
        acc += p * v;
    }
    acc = acc / (ssum + 1e-16f) + b3[c];
    float v = acc, v2 = acc * acc;
#pragma unroll
    for (int off = 1; off < 16; off <<= 1) { v += __shfl_xor(v, off, 16); v2 += __shfl_xor(v2, off, 16); }
    float mean = v * (1.0f / COUT);
    float var = v2 * (1.0f / COUT) - mean * mean;
    out[i * COUT + c] = (acc - mean) * rsqrtf(var + 1e-5f) * g3[c] + be3[c];
}

extern "C" void kernel_launch(void* const* d_in, const int* in_sizes, int n_in,
                              void* d_out, int out_size, void* d_ws, size_t ws_size,
                              hipStream_t stream) {
    const float* x   = (const float*)d_in[0];
    const int*   ei  = (const int*)d_in[1];
    const float* Wp  = (const float*)d_in[2];
    const float* bp  = (const float*)d_in[3];
    const float* g0  = (const float*)d_in[4];
    const float* b0  = (const float*)d_in[5];
    const float* W1  = (const float*)d_in[6];
    const float* as1 = (const float*)d_in[7];
    const float* ad1 = (const float*)d_in[8];
    const float* b1  = (const float*)d_in[9];
    const float* g1  = (const float*)d_in[10];
    const float* be1 = (const float*)d_in[11];
    const float* W2  = (const float*)d_in[12];
    const float* as2 = (const float*)d_in[13];
    const float* ad2 = (const float*)d_in[14];
    const float* b2  = (const float*)d_in[15];
    const float* g2  = (const float*)d_in[16];
    const float* be2 = (const float*)d_in[17];
    const float* W3  = (const float*)d_in[18];
    const float* as3 = (const float*)d_in[19];
    const float* ad3 = (const float*)d_in[20];
    const float* b3  = (const float*)d_in[21];
    const float* g3  = (const float*)d_in[22];
    const float* be3 = (const float*)d_in[23];

    // ---- workspace carve (~40 MB) ----
    ushort* B0  = (ushort*)d_ws;
    ushort* B1  = B0 + NF;
    ushort* B2  = B1 + NF;
    ushort* xbf = B2 + NF;                 // NNODES*CIN
    ushort* Wpt = xbf + (size_t)NNODES * CIN;   // CIN*CH
    ushort* W1t = Wpt + (size_t)CIN * CH;       // CH*CH
    ushort* W2t = W1t + (size_t)CH * CH;
    float* als = (float*)(W2t + (size_t)CH * CH);
    float* ald = als + NNODES * NHEAD;
    float* h3  = ald + NNODES * NHEAD;          // NNODES*COUT
    int* deg = (int*)(h3 + (size_t)NNODES * COUT);
    int* stA = deg + NNODES;
    int* cur = stA + NNODES;
    int* csr = cur + NNODES;

    // ---- CSR build ----
    hipMemsetAsync(deg, 0, NNODES * sizeof(int), stream);
    hipMemsetAsync(cur, 0, NNODES * sizeof(int), stream);
    count_deg_k<<<(ETOT + 255) / 256, 256, 0, stream>>>(ei, deg);
    scan_k<<<1, 512, 0, stream>>>(deg, stA);
    scatter_k<<<(ETOT + 255) / 256, 256, 0, stream>>>(ei, stA, cur, csr);

    // ---- converts ----
    convert_x_k<<<(NNODES * CIN / 4 + 255) / 256, 256, 0, stream>>>(x, xbf);
    convert_wT_k<<<dim3(CH / 32, CIN / 32), 256, 0, stream>>>(Wp, Wpt, CIN, CH);
    convert_wT_k<<<dim3(CH / 32, CH / 32), 256, 0, stream>>>(W1, W1t, CH, CH);
    convert_wT_k<<<dim3(CH / 32, CH / 32), 256, 0, stream>>>(W2, W2t, CH, CH);

    dim3 gg((NNODES + 63) / 64, CH / 64);

    // ---- input projection + LN + ELU ----
    gemm_mfma<<<gg, 256, 0, stream>>>(xbf, Wpt, bp, B0, nullptr, nullptr, nullptr, nullptr, NNODES, CIN);
    ln_elu_k<<<NNODES, 128, 0, stream>>>(B0, g0, b0, B1);

    // ---- GAT layer 1: h=gemm(B1)+logits -> B2,als,ald; fused agg(resid=B1) -> B0 ----
    gemm_mfma<<<gg, 256, 0, stream>>>(B1, W1t, nullptr, B2, as1, ad1, als, ald, NNODES, CH);
    agg_ln_k<<<NNODES, 256, 0, stream>>>(B2, als, ald, stA, deg, csr, b1, g1, be1, B1, B0);

    // ---- GAT layer 2: h=gemm(B0)+logits -> B1,als,ald; fused agg(resid=B0) -> B2 ----
    gemm_mfma<<<gg, 256, 0, stream>>>(B0, W2t, nullptr, B1, as2, ad2, als, ald, NNODES, CH);
    agg_ln_k<<<NNODES, 256, 0, stream>>>(B1, als, ald, stA, deg, csr, b2, g2, be2, B0, B2);

    // ---- final layer (B2 -> d_out): small GEMM + fully fused attention ----
    gemm_small_k<<<(NNODES + 15) / 16, 256, 0, stream>>>(B2, W3, h3);
    agg16f_k<<<(NNODES + 15) / 16, 256, 0, stream>>>(h3, as3, ad3, stA, deg, csr, b3, g3, be3, (float*)d_out);
}